// Round 7
// baseline (822.383 us; speedup 1.0000x reference)
//
#include <hip/hip_runtime.h>
#include <math.h>

// Model dims (fixed by the reference)
#define T_DIM 512
#define B_DIM 64
#define J_DIM 256
#define H_DIM 256
#define K_TAP 25
#define NL    3
#define M_DIM (T_DIM*B_DIM)   // 32768 rows = (t,b)
#define NBH   (B_DIM*H_DIM)   // 16384
#define STATB 128
#define GUARD_ROWS 1536                  // 64*24 zero rows before row 0
#define GUARD_BYTES (GUARD_ROWS*J_DIM)   // 393216

// conv GEMM tiling: 64(M) x 64(N) block, 4 waves (2x2), wave tile 32x32, BK=64
#define MB 64
#define NB 64
#define BK 64
#define NST (K_TAP*(J_DIM/BK))   // 100 K-steps

typedef __attribute__((ext_vector_type(4))) int   i32x4;

__device__ __forceinline__ void gl16(const void* g, void* l){ // async global->LDS, 16B/lane
  __builtin_amdgcn_global_load_lds((const __attribute__((address_space(1))) unsigned int*)g,
                                   (__attribute__((address_space(3))) unsigned int*)l, 16, 0, 0);
}

// ---------------------------------------------------------------------------
// 0a) zero the causal guard region (d_ws is poisoned, must zero every call)
// ---------------------------------------------------------------------------
__global__ void zero_guard_k(unsigned char* __restrict__ g){
  *(uint4*)(g + (size_t)(blockIdx.x*256 + threadIdx.x)*16) = (uint4){0,0,0,0};
}

// 0b) cast f32 binary input -> u8 spikes
__global__ void cast_u8_k(const float* __restrict__ x, unsigned char* __restrict__ s){
  const int i = blockIdx.x*256 + threadIdx.x;       // one float4 per thread
  const float4 v = *(const float4*)(x + (size_t)i*4);
  uchar4 o; o.x=(unsigned char)v.x; o.y=(unsigned char)v.y;
  o.z=(unsigned char)v.z; o.w=(unsigned char)v.w;
  *(uchar4*)(s + (size_t)i*4) = o;
}

// ---------------------------------------------------------------------------
// 1) DCLS gaussian kernel -> 23-bit fixed point, 3 signed-i8 digit planes.
//    kd[d][o][j] = W[o,j]*gnorm[o,j,k=24-d].  Per-column power-of-2 scale s_o;
//    q = rint(kd/s_o * 2^22); q = b2*2^16 + b1*2^8 + b0 exactly.
//    fsc[o] = s_o * 2^-22 (exact power of 2).
// ---------------------------------------------------------------------------
__global__ void build_kern_k(const float* __restrict__ W, const float* __restrict__ P,
                             signed char* __restrict__ k0, signed char* __restrict__ k1,
                             signed char* __restrict__ k2, float* __restrict__ fsc, int layer){
  __shared__ float red[256];
  const int o = blockIdx.x, j = threadIdx.x;
  const float w = W[(layer*H_DIM + o)*J_DIM + j];
  const float p = P[(layer*H_DIM + o)*J_DIM + j];
  const float c = p + 12.0f;              // P + K//2
  const float sg = 0.77f;                 // |0.5| + 0.27
  float v[K_TAP]; float ssum = 0.f;
#pragma unroll
  for(int k=0;k<K_TAP;k++){ float z = ((float)k - c)/sg; v[k] = expf(-0.5f*z*z); ssum += v[k]; }
  const float inv = 1.0f/(ssum + 1e-7f);
  float mv = 0.f;
#pragma unroll
  for(int k=0;k<K_TAP;k++){ v[k] = w * (v[k]*inv); mv = fmaxf(mv, fabsf(v[k])); }
  red[j] = mv; __syncthreads();
  for(int st=128; st; st>>=1){ if(j<st) red[j] = fmaxf(red[j], red[j+st]); __syncthreads(); }
  int e; frexpf(red[0], &e);              // maxv = f*2^e, f in [0.5,1)
  const float invq = ldexpf(1.f, 22 - e); // 2^22 / s_o
#pragma unroll
  for(int k=0;k<K_TAP;k++){
    const int d = (K_TAP-1)-k;
    int q = (int)lrintf(v[k]*invq);
    const int b0 = (int)(signed char)(q & 0xFF); q = (q - b0) >> 8;
    const int b1 = (int)(signed char)(q & 0xFF); q = (q - b1) >> 8;
    const size_t idx = (size_t)(d*H_DIM + o)*J_DIM + j;
    k0[idx] = (signed char)b0; k1[idx] = (signed char)b1; k2[idx] = (signed char)q;
  }
  if(j==0) fsc[o] = ldexpf(1.f, e - 22);
}

// ---------------------------------------------------------------------------
// 2) Delayed causal conv as EXACT i8 MFMA GEMM (3 digit planes, i32 acc).
//    64x64 block, 4 waves 2x2, wave tile 32x32, mfma_i32_16x16x64_i8, BK=64.
//    Occupancy-focused: acc=48 regs -> 4 waves/SIMD; LDS 28KB (A single-buf
//    4KB + B dbuf 24KB) -> 4-5 blocks/CU. A-frag reads precede barrier1 so
//    re-staging A into the same buffer after the barrier is race-free (the
//    compiler drains lgkmcnt before s_barrier). Conflict-free via source-slot
//    swizzle (m173): slot ^= (row>>1)&3, read slot ((lane>>4)^(lane>>1))&3.
// ---------------------------------------------------------------------------
__global__ __launch_bounds__(256,4) void conv_mfma_k(const unsigned char* __restrict__ spk,
    const signed char* __restrict__ k0, const signed char* __restrict__ k1,
    const signed char* __restrict__ k2, const float* __restrict__ fsc,
    float* __restrict__ y){
  __shared__ unsigned char Abuf[4096];        // A[64][64] u8, single-buffered
  __shared__ unsigned char Bbuf[2][12288];    // per buf: B0|B1|B2 each [64][64]
  const int tid = threadIdx.x, lane = tid & 63, wave = tid >> 6;
  const int m0 = blockIdx.x * MB, n0 = blockIdx.y * NB;
  const int wm0 = (wave >> 1) << 5;   // 0 / 32
  const int wn0 = (wave & 1) << 5;    // 0 / 32

  const int srow  = wave*16 + (lane >> 2);           // staging row 0..63
  const int sslot = ((lane & 3) ^ (srow >> 1)) & 3;  // swizzled source 16B slot
  const int rslot = ((((lane>>4) ^ (lane>>1)) & 3) << 4);  // read slot byte off

  i32x4 acc0[2][2], acc1[2][2], acc2[2][2];
#pragma unroll
  for(int m=0;m<2;m++)
#pragma unroll
    for(int n=0;n<2;n++){
      acc0[m][n] = (i32x4){0,0,0,0};
      acc1[m][n] = (i32x4){0,0,0,0};
      acc2[m][n] = (i32x4){0,0,0,0};
    }

#define STAGE_A(t) do{ \
    const int d_ = (t)>>2, jc_ = ((t)&3)<<6; \
    const unsigned char* as_ = spk + (size_t)(m0 + srow - (d_<<6) + GUARD_ROWS)*J_DIM + jc_ + sslot*16; \
    gl16(as_, &Abuf[0] + wave*1024); \
  }while(0)

#define STAGE_B(buf,t) do{ \
    const int d_ = (t)>>2, jc_ = ((t)&3)<<6; \
    const size_t bo_ = (size_t)(d_*H_DIM + n0 + srow)*J_DIM + jc_ + sslot*16; \
    gl16(k0 + bo_, &Bbuf[buf][0]    + wave*1024); \
    gl16(k1 + bo_, &Bbuf[buf][4096] + wave*1024); \
    gl16(k2 + bo_, &Bbuf[buf][8192] + wave*1024); \
  }while(0)

  // prologue: stage step 0
  STAGE_A(0);
  STAGE_B(0,0);
  __syncthreads();       // compiler drains vmcnt -> buffers ready

  int cur = 0;
  for(int t=0; t<NST; ++t){
    const int nxt = cur ^ 1;
    // A-frag reads BEFORE barrier1 (A is single-buffered)
    i32x4 af[2];
#pragma unroll
    for(int m=0;m<2;m++)
      af[m] = *(const i32x4*)(Abuf + (wm0 + m*16 + (lane&15))*64 + rslot);
    __syncthreads();                               // all waves done reading A
    if(t+1 < NST){ STAGE_A(t+1); STAGE_B(nxt, t+1); }   // issue early (T14)
    const unsigned char* Bc = &Bbuf[cur][0];
    __builtin_amdgcn_s_setprio(1);
#pragma unroll
    for(int n=0;n<2;n++){
      const int ro = (wn0 + n*16 + (lane&15))*64 + rslot;
      const i32x4 b0 = *(const i32x4*)(Bc + ro);
      const i32x4 b1 = *(const i32x4*)(Bc + 4096 + ro);
      const i32x4 b2 = *(const i32x4*)(Bc + 8192 + ro);
#pragma unroll
      for(int m=0;m<2;m++){
        acc0[m][n] = __builtin_amdgcn_mfma_i32_16x16x64_i8(af[m], b0, acc0[m][n], 0,0,0);
        acc1[m][n] = __builtin_amdgcn_mfma_i32_16x16x64_i8(af[m], b1, acc1[m][n], 0,0,0);
        acc2[m][n] = __builtin_amdgcn_mfma_i32_16x16x64_i8(af[m], b2, acc2[m][n], 0,0,0);
      }
    }
    __builtin_amdgcn_s_setprio(0);
    __syncthreads();     // drains vmcnt(0): staged A + B[nxt] visible
    cur = nxt;
  }

  // epilogue: C/D mapping col=lane&15, row=(lane>>4)*4+r [shape-determined].
  // Exact int64 digit recombine, then one float rounding via pow2 scale.
  const int r0 = m0 + wm0 + ((lane>>4)<<2);
  const int c0 = n0 + wn0 + (lane&15);
  const double f0 = (double)fsc[c0];
  const double f1 = (double)fsc[c0+16];
#pragma unroll
  for(int m=0;m<2;m++)
#pragma unroll
    for(int n=0;n<2;n++){
      const double fs = n ? f1 : f0;
#pragma unroll
      for(int r=0;r<4;r++){
        const long long cmb = ((long long)acc2[m][n][r] << 16)
                            + ((long long)acc1[m][n][r] << 8)
                            +  (long long)acc0[m][n][r];
        y[(size_t)(r0 + m*16 + r)*H_DIM + c0 + n*16] = (float)((double)cmb * fs);
      }
    }
#undef STAGE_A
#undef STAGE_B
}

// ---------------------------------------------------------------------------
// 3) BatchNorm training stats (two-stage, fp64 accumulators, fixed order)
// ---------------------------------------------------------------------------
__global__ void bn_stats_k(const float* __restrict__ y, double* __restrict__ part){
  const int o   = threadIdx.x;
  const int blk = blockIdx.x;         // 0..127
  const int rows = M_DIM / STATB;     // 256
  const float* p = y + (size_t)(blk*rows)*H_DIM + o;
  double s = 0.0, s2 = 0.0;
  for(int r=0;r<rows;r++){
    double v = (double)p[(size_t)r*H_DIM];
    s  += v;
    s2 += v*v;
  }
  part[blk*H_DIM + o]               = s;
  part[STATB*H_DIM + blk*H_DIM + o] = s2;
}

__global__ void bn_final_k(const double* __restrict__ part, float* __restrict__ sc,
                           float* __restrict__ sh, const float* __restrict__ gamma_,
                           const float* __restrict__ bb_, int layer){
  const int o = threadIdx.x;
  double s = 0.0, s2 = 0.0;
  for(int b=0;b<STATB;b++){
    s  += part[b*H_DIM + o];
    s2 += part[STATB*H_DIM + b*H_DIM + o];
  }
  const double inv_n = 1.0 / (double)M_DIM;
  const double m   = s * inv_n;
  const double var = s2 * inv_n - m*m;      // biased, like jnp.var
  const double rs  = 1.0 / sqrt(var + (double)1e-5f);
  const float g  = gamma_[layer*H_DIM + o];
  const float bv = bb_[layer*H_DIM + o];
  const float scale = (float)((double)g * rs);
  sc[o] = scale;
  sh[o] = (float)((double)bv - m*(double)scale);
}

// ---------------------------------------------------------------------------
// 4) LIF soft-reset scan. One thread per (b,h), 16-deep prefetch.
//    TOUT=u8 inter-layer spikes, f32 final output (in-place on d_out).
//    NOTE: no __restrict__ on yin/sout — they alias for the final layer.
// ---------------------------------------------------------------------------
template<typename TOUT>
__global__ void lif_k(const float* yin, TOUT* sout,
                      const float* __restrict__ sc_, const float* __restrict__ sh_,
                      const float* __restrict__ beta_, const float* __restrict__ U0_,
                      int layer){
  const int idx = blockIdx.x*64 + threadIdx.x;   // 0..16383 = b*256+h
  const int h = idx & (H_DIM-1);
  const float scale = sc_[h];
  const float shift = sh_[h];
  const float beta  = beta_[layer*H_DIM + h];
  const float ombeta = 1.0f - beta;
  float U = U0_[layer*NBH + idx];
  float S = 0.f;
  float cur[16];
#pragma unroll
  for(int i=0;i<16;i++) cur[i] = yin[(size_t)i*NBH + idx];
  for(int t=0;t<T_DIM;t+=16){
    float nx[16];
#pragma unroll
    for(int i=0;i<16;i++){
      const int tt = t + 16 + i;
      nx[i] = (tt < T_DIM) ? yin[(size_t)tt*NBH + idx] : 0.f;
    }
#pragma unroll
    for(int i=0;i<16;i++){
      const float yv = fmaf(cur[i], scale, shift);
      U = beta*(U - S) + ombeta*yv;
      S = (U > 1.0f) ? 1.f : 0.f;              // (U - THETA) > 0
      sout[(size_t)(t+i)*NBH + idx] = (TOUT)S;
    }
#pragma unroll
    for(int i=0;i<16;i++) cur[i] = nx[i];
  }
}

// ---------------------------------------------------------------------------
// Launch. ws layout (14.22 MB):
//   spk  [0,          8,781,824)    guard(393216 zeros) + 32768*256 u8 spikes
//   k0   [8,781,824, 10,420,224)    25*256*256 i8 digit 0 (2^0)
//   k1   [10,420,224,12,058,624)    25*256*256 i8 digit 1 (2^8)
//   k2   [12,058,624,13,697,024)    25*256*256 i8 digit 2 (2^16)
//   fsc  [13,697,024,+1024)         256 f32 per-column scale
//   part [13,698,048,14,222,336)    2*128*256 f64 BN partials
//   sc   [14,222,336,+1024) f32 ; sh [14,223,360,+1024) f32
// Conv y always lands in d_out (fully rewritten each layer before any read).
// ---------------------------------------------------------------------------
extern "C" void kernel_launch(void* const* d_in, const int* in_sizes, int n_in,
                              void* d_out, int out_size, void* d_ws, size_t ws_size,
                              hipStream_t stream){
  const float* x    = (const float*)d_in[0];
  const float* W    = (const float*)d_in[1];
  const float* P    = (const float*)d_in[2];
  const float* beta = (const float*)d_in[3];
  const float* gam  = (const float*)d_in[4];
  const float* bb   = (const float*)d_in[5];
  const float* U0   = (const float*)d_in[6];
  float* out = (float*)d_out;

  char* ws = (char*)d_ws;
  unsigned char* spk  = (unsigned char*)ws;                 // guarded base
  unsigned char* spkd = spk + GUARD_BYTES;                  // data region
  signed char*   k0   = (signed char*)(ws + 8781824);
  signed char*   k1   = (signed char*)(ws + 10420224);
  signed char*   k2   = (signed char*)(ws + 12058624);
  float*         fsc  = (float*)(ws + 13697024);
  double*        part = (double*)(ws + 13698048);
  float*         sc   = (float*)(ws + 14222336);
  float*         sh   = sc + 256;

  zero_guard_k<<<dim3(GUARD_BYTES/4096), dim3(256), 0, stream>>>(spk);
  cast_u8_k<<<dim3((M_DIM*J_DIM)/1024), dim3(256), 0, stream>>>(x, spkd);

  for(int l=0;l<NL;l++){
    build_kern_k<<<dim3(H_DIM), dim3(J_DIM), 0, stream>>>(W, P, k0, k1, k2, fsc, l);
    conv_mfma_k<<<dim3(M_DIM/MB, H_DIM/NB), dim3(256), 0, stream>>>(spk, k0, k1, k2, fsc, out);
    bn_stats_k<<<dim3(STATB), dim3(H_DIM), 0, stream>>>(out, part);
    bn_final_k<<<dim3(1), dim3(H_DIM), 0, stream>>>(part, sc, sh, gam, bb, l);
    if(l < NL-1) lif_k<unsigned char><<<dim3(NBH/64), dim3(64), 0, stream>>>(out, spkd, sc, sh, beta, U0, l);
    else         lif_k<float>        <<<dim3(NBH/64), dim3(64), 0, stream>>>(out, out, sc, sh, beta, U0, l);
  }
}

// Round 8
// 579.268 us; speedup vs baseline: 1.4197x; 1.4197x over previous
//
#include <hip/hip_runtime.h>
#include <math.h>

// Model dims (fixed by the reference)
#define T_DIM 512
#define B_DIM 64
#define J_DIM 256
#define H_DIM 256
#define K_TAP 25
#define NL    3
#define M_DIM (T_DIM*B_DIM)   // 32768 rows = (t,b)
#define NBH   (B_DIM*H_DIM)   // 16384
#define STATB 128
#define GUARD_ROWS 1536                  // 64*24 zero rows before row 0
#define GUARD_BYTES (GUARD_ROWS*J_DIM)   // 393216

// conv GEMM tiling: 128(M) x 64(N) block, 4 waves (2x2), wave tile 64x32, BK=64
#define MB 128
#define NB 64
#define BK 64
#define NST (K_TAP*(J_DIM/BK))   // 100 K-steps
#define BUFB 20480                // bytes per LDS buffer set: A 8K | B0|B1|B2 4K each

typedef __attribute__((ext_vector_type(4))) int   i32x4;

__device__ __forceinline__ void gl16(const void* g, void* l){ // async global->LDS, 16B/lane
  __builtin_amdgcn_global_load_lds((const __attribute__((address_space(1))) unsigned int*)g,
                                   (__attribute__((address_space(3))) unsigned int*)l, 16, 0, 0);
}

// ---------------------------------------------------------------------------
// 0a) zero the causal guard region (d_ws is poisoned, must zero every call)
// ---------------------------------------------------------------------------
__global__ void zero_guard_k(unsigned char* __restrict__ g){
  *(uint4*)(g + (size_t)(blockIdx.x*256 + threadIdx.x)*16) = (uint4){0,0,0,0};
}

// 0b) cast f32 binary input -> u8 spikes
__global__ void cast_u8_k(const float* __restrict__ x, unsigned char* __restrict__ s){
  const int i = blockIdx.x*256 + threadIdx.x;       // one float4 per thread
  const float4 v = *(const float4*)(x + (size_t)i*4);
  uchar4 o; o.x=(unsigned char)v.x; o.y=(unsigned char)v.y;
  o.z=(unsigned char)v.z; o.w=(unsigned char)v.w;
  *(uchar4*)(s + (size_t)i*4) = o;
}

// ---------------------------------------------------------------------------
// 1) DCLS gaussian kernel -> 23-bit fixed point, 3 signed-i8 digit planes.
//    kd[d][o][j] = W[o,j]*gnorm[o,j,k=24-d].  Per-column power-of-2 scale s_o;
//    q = rint(kd/s_o * 2^22); q = b2*2^16 + b1*2^8 + b0 exactly.
//    fsc[o] = s_o * 2^-22 (exact power of 2).
// ---------------------------------------------------------------------------
__global__ void build_kern_k(const float* __restrict__ W, const float* __restrict__ P,
                             signed char* __restrict__ k0, signed char* __restrict__ k1,
                             signed char* __restrict__ k2, float* __restrict__ fsc, int layer){
  __shared__ float red[256];
  const int o = blockIdx.x, j = threadIdx.x;
  const float w = W[(layer*H_DIM + o)*J_DIM + j];
  const float p = P[(layer*H_DIM + o)*J_DIM + j];
  const float c = p + 12.0f;              // P + K//2
  const float sg = 0.77f;                 // |0.5| + 0.27
  float v[K_TAP]; float ssum = 0.f;
#pragma unroll
  for(int k=0;k<K_TAP;k++){ float z = ((float)k - c)/sg; v[k] = expf(-0.5f*z*z); ssum += v[k]; }
  const float inv = 1.0f/(ssum + 1e-7f);
  float mv = 0.f;
#pragma unroll
  for(int k=0;k<K_TAP;k++){ v[k] = w * (v[k]*inv); mv = fmaxf(mv, fabsf(v[k])); }
  red[j] = mv; __syncthreads();
  for(int st=128; st; st>>=1){ if(j<st) red[j] = fmaxf(red[j], red[j+st]); __syncthreads(); }
  int e; frexpf(red[0], &e);              // maxv = f*2^e, f in [0.5,1)
  const float invq = ldexpf(1.f, 22 - e); // 2^22 / s_o
#pragma unroll
  for(int k=0;k<K_TAP;k++){
    const int d = (K_TAP-1)-k;
    int q = (int)lrintf(v[k]*invq);
    const int b0 = (int)(signed char)(q & 0xFF); q = (q - b0) >> 8;
    const int b1 = (int)(signed char)(q & 0xFF); q = (q - b1) >> 8;
    const size_t idx = (size_t)(d*H_DIM + o)*J_DIM + j;
    k0[idx] = (signed char)b0; k1[idx] = (signed char)b1; k2[idx] = (signed char)q;
  }
  if(j==0) fsc[o] = ldexpf(1.f, e - 22);
}

// ---------------------------------------------------------------------------
// 2) Delayed causal conv as EXACT i8 MFMA GEMM (3 digit planes, i32 acc).
//    128x64 block, 4 waves 2x2, wave tile 64x32, mfma_i32_16x16x64_i8, BK=64.
//    TRIPLE-buffered LDS + counted vmcnt(5) + ONE raw barrier per K-step
//    (T4: loads never drained to 0 in the main loop). Stage depth 2.
//    Race-free: reads of buf[t%3] retire before each wave's barrier arrival
//    (lgkm before MFMA issue); buf[t%3] is next overwritten by STAGE(t+3),
//    issued only after barrier(t+1) - i.e. after all waves read it.
//    Conflict-free LDS via source-slot swizzle (m173): phys slot p of row r
//    holds logical slot p^((r>>1)&3); read slot ((lane>>4)^(lane>>1))&3.
//    XCD swizzle (T1): n0-major chunks -> per-XCD L2-resident B panel.
// ---------------------------------------------------------------------------
__global__ __launch_bounds__(256,2) void conv_mfma_k(const unsigned char* __restrict__ spk,
    const signed char* __restrict__ k0, const signed char* __restrict__ k1,
    const signed char* __restrict__ k2, const float* __restrict__ fsc,
    float* __restrict__ y){
  __shared__ unsigned char lds[3][BUFB];  // per set: A[128][64] | B0|B1|B2 [64][64]
  const int tid = threadIdx.x, lane = tid & 63, wave = tid >> 6;
  // XCD-aware n0-major decode: xcd = bid%8 owns 128 consecutive q's (one n-panel)
  const int bid = blockIdx.x;                      // 0..1023
  const int q   = (bid & 7)*128 + (bid >> 3);
  const int m0  = (q & 255) * MB;
  const int n0  = (q >> 8) * NB;
  const int wm0 = (wave >> 1) << 6;   // 0 / 64
  const int wn0 = (wave & 1) << 5;    // 0 / 32

  const int srow  = tid >> 2;                        // staging row 0..63
  const int sslot = ((tid & 3) ^ (srow >> 1)) & 3;   // swizzled source 16B slot
  const int rslot = ((((lane>>4) ^ (lane>>1)) & 3) << 4);  // read slot byte off

  i32x4 acc0[4][2], acc1[4][2], acc2[4][2];
#pragma unroll
  for(int m=0;m<4;m++)
#pragma unroll
    for(int n=0;n<2;n++){
      acc0[m][n] = (i32x4){0,0,0,0};
      acc1[m][n] = (i32x4){0,0,0,0};
      acc2[m][n] = (i32x4){0,0,0,0};
    }

#define STAGE(base,t) do{ \
    const int d_ = (t)>>2, jc_ = ((t)&3)<<6; \
    unsigned char* lb_ = (base); \
    const unsigned char* as_ = spk + (size_t)(m0 + srow - (d_<<6) + GUARD_ROWS)*J_DIM + jc_ + sslot*16; \
    gl16(as_,                    lb_        + wave*1024); \
    gl16(as_ + (size_t)64*J_DIM, lb_ + 4096 + wave*1024); \
    const size_t bo_ = (size_t)(d_*H_DIM + n0 + srow)*J_DIM + jc_ + sslot*16; \
    gl16(k0 + bo_, lb_ + 8192  + wave*1024); \
    gl16(k1 + bo_, lb_ + 12288 + wave*1024); \
    gl16(k2 + bo_, lb_ + 16384 + wave*1024); \
  }while(0)

  unsigned char* const L = &lds[0][0];

  // prologue: stage t=0 -> set0, t=1 -> set1 (depth-2 prefetch)
  STAGE(L, 0);
  STAGE(L + BUFB, 1);

  int rb = 0;   // read set for iter t (t % 3)
  for(int t=0; t<NST; ++t){
    if(t < NST-1) asm volatile("s_waitcnt vmcnt(5)" ::: "memory");  // t's 5 loads landed
    else          asm volatile("s_waitcnt vmcnt(0)" ::: "memory");  // final drain
    __builtin_amdgcn_s_barrier();
    __builtin_amdgcn_sched_barrier(0);
    unsigned char* Lb = L + rb*BUFB;
    i32x4 af[4], b0f[2], b1f[2], b2f[2];
#pragma unroll
    for(int m=0;m<4;m++)
      af[m] = *(const i32x4*)(Lb + (wm0 + m*16 + (lane&15))*64 + rslot);
#pragma unroll
    for(int n=0;n<2;n++){
      const int ro = (wn0 + n*16 + (lane&15))*64 + rslot;
      b0f[n] = *(const i32x4*)(Lb + 8192  + ro);
      b1f[n] = *(const i32x4*)(Lb + 12288 + ro);
      b2f[n] = *(const i32x4*)(Lb + 16384 + ro);
    }
    if(t+2 < NST){
      int sb = rb + 2; if(sb >= 3) sb -= 3;
      STAGE(L + sb*BUFB, t+2);          // issue early (T14); lands by iter t+2
    }
    __builtin_amdgcn_s_setprio(1);
#pragma unroll
    for(int m=0;m<4;m++)
#pragma unroll
      for(int n=0;n<2;n++){
        acc0[m][n] = __builtin_amdgcn_mfma_i32_16x16x64_i8(af[m], b0f[n], acc0[m][n], 0,0,0);
        acc1[m][n] = __builtin_amdgcn_mfma_i32_16x16x64_i8(af[m], b1f[n], acc1[m][n], 0,0,0);
        acc2[m][n] = __builtin_amdgcn_mfma_i32_16x16x64_i8(af[m], b2f[n], acc2[m][n], 0,0,0);
      }
    __builtin_amdgcn_s_setprio(0);
    rb += 1; if(rb == 3) rb = 0;
  }

  // epilogue: C/D mapping col=lane&15, row=(lane>>4)*4+r [shape-determined].
  // Exact int64 digit recombine, then one float rounding via pow2 scale.
  const int r0 = m0 + wm0 + ((lane>>4)<<2);
  const int c0 = n0 + wn0 + (lane&15);
  const double f0 = (double)fsc[c0];
  const double f1 = (double)fsc[c0+16];
#pragma unroll
  for(int m=0;m<4;m++)
#pragma unroll
    for(int n=0;n<2;n++){
      const double fs = n ? f1 : f0;
#pragma unroll
      for(int r=0;r<4;r++){
        const long long cmb = ((long long)acc2[m][n][r] << 16)
                            + ((long long)acc1[m][n][r] << 8)
                            +  (long long)acc0[m][n][r];
        y[(size_t)(r0 + m*16 + r)*H_DIM + c0 + n*16] = (float)((double)cmb * fs);
      }
    }
#undef STAGE
}

// ---------------------------------------------------------------------------
// 3) BatchNorm training stats (two-stage, fp64 accumulators, fixed order)
// ---------------------------------------------------------------------------
__global__ void bn_stats_k(const float* __restrict__ y, double* __restrict__ part){
  const int o   = threadIdx.x;
  const int blk = blockIdx.x;         // 0..127
  const int rows = M_DIM / STATB;     // 256
  const float* p = y + (size_t)(blk*rows)*H_DIM + o;
  double s = 0.0, s2 = 0.0;
  for(int r=0;r<rows;r++){
    double v = (double)p[(size_t)r*H_DIM];
    s  += v;
    s2 += v*v;
  }
  part[blk*H_DIM + o]               = s;
  part[STATB*H_DIM + blk*H_DIM + o] = s2;
}

__global__ void bn_final_k(const double* __restrict__ part, float* __restrict__ sc,
                           float* __restrict__ sh, const float* __restrict__ gamma_,
                           const float* __restrict__ bb_, int layer){
  const int o = threadIdx.x;
  double s = 0.0, s2 = 0.0;
  for(int b=0;b<STATB;b++){
    s  += part[b*H_DIM + o];
    s2 += part[STATB*H_DIM + b*H_DIM + o];
  }
  const double inv_n = 1.0 / (double)M_DIM;
  const double m   = s * inv_n;
  const double var = s2 * inv_n - m*m;      // biased, like jnp.var
  const double rs  = 1.0 / sqrt(var + (double)1e-5f);
  const float g  = gamma_[layer*H_DIM + o];
  const float bv = bb_[layer*H_DIM + o];
  const float scale = (float)((double)g * rs);
  sc[o] = scale;
  sh[o] = (float)((double)bv - m*(double)scale);
}

// ---------------------------------------------------------------------------
// 4) LIF soft-reset scan. One thread per (b,h), 16-deep prefetch.
//    TOUT=u8 inter-layer spikes, f32 final output (in-place on d_out).
//    NOTE: no __restrict__ on yin/sout — they alias for the final layer.
// ---------------------------------------------------------------------------
template<typename TOUT>
__global__ void lif_k(const float* yin, TOUT* sout,
                      const float* __restrict__ sc_, const float* __restrict__ sh_,
                      const float* __restrict__ beta_, const float* __restrict__ U0_,
                      int layer){
  const int idx = blockIdx.x*64 + threadIdx.x;   // 0..16383 = b*256+h
  const int h = idx & (H_DIM-1);
  const float scale = sc_[h];
  const float shift = sh_[h];
  const float beta  = beta_[layer*H_DIM + h];
  const float ombeta = 1.0f - beta;
  float U = U0_[layer*NBH + idx];
  float S = 0.f;
  float cur[16];
#pragma unroll
  for(int i=0;i<16;i++) cur[i] = yin[(size_t)i*NBH + idx];
  for(int t=0;t<T_DIM;t+=16){
    float nx[16];
#pragma unroll
    for(int i=0;i<16;i++){
      const int tt = t + 16 + i;
      nx[i] = (tt < T_DIM) ? yin[(size_t)tt*NBH + idx] : 0.f;
    }
#pragma unroll
    for(int i=0;i<16;i++){
      const float yv = fmaf(cur[i], scale, shift);
      U = beta*(U - S) + ombeta*yv;
      S = (U > 1.0f) ? 1.f : 0.f;              // (U - THETA) > 0
      sout[(size_t)(t+i)*NBH + idx] = (TOUT)S;
    }
#pragma unroll
    for(int i=0;i<16;i++) cur[i] = nx[i];
  }
}

// ---------------------------------------------------------------------------
// Launch. ws layout (14.22 MB):
//   spk  [0,          8,781,824)    guard(393216 zeros) + 32768*256 u8 spikes
//   k0   [8,781,824, 10,420,224)    25*256*256 i8 digit 0 (2^0)
//   k1   [10,420,224,12,058,624)    25*256*256 i8 digit 1 (2^8)
//   k2   [12,058,624,13,697,024)    25*256*256 i8 digit 2 (2^16)
//   fsc  [13,697,024,+1024)         256 f32 per-column scale
//   part [13,698,048,14,222,336)    2*128*256 f64 BN partials
//   sc   [14,222,336,+1024) f32 ; sh [14,223,360,+1024) f32
// Conv y always lands in d_out (fully rewritten each layer before any read).
// ---------------------------------------------------------------------------
extern "C" void kernel_launch(void* const* d_in, const int* in_sizes, int n_in,
                              void* d_out, int out_size, void* d_ws, size_t ws_size,
                              hipStream_t stream){
  const float* x    = (const float*)d_in[0];
  const float* W    = (const float*)d_in[1];
  const float* P    = (const float*)d_in[2];
  const float* beta = (const float*)d_in[3];
  const float* gam  = (const float*)d_in[4];
  const float* bb   = (const float*)d_in[5];
  const float* U0   = (const float*)d_in[6];
  float* out = (float*)d_out;

  char* ws = (char*)d_ws;
  unsigned char* spk  = (unsigned char*)ws;                 // guarded base
  unsigned char* spkd = spk + GUARD_BYTES;                  // data region
  signed char*   k0   = (signed char*)(ws + 8781824);
  signed char*   k1   = (signed char*)(ws + 10420224);
  signed char*   k2   = (signed char*)(ws + 12058624);
  float*         fsc  = (float*)(ws + 13697024);
  double*        part = (double*)(ws + 13698048);
  float*         sc   = (float*)(ws + 14222336);
  float*         sh   = sc + 256;

  zero_guard_k<<<dim3(GUARD_BYTES/4096), dim3(256), 0, stream>>>(spk);
  cast_u8_k<<<dim3((M_DIM*J_DIM)/1024), dim3(256), 0, stream>>>(x, spkd);

  for(int l=0;l<NL;l++){
    build_kern_k<<<dim3(H_DIM), dim3(J_DIM), 0, stream>>>(W, P, k0, k1, k2, fsc, l);
    conv_mfma_k<<<dim3((M_DIM/MB)*(H_DIM/NB)), dim3(256), 0, stream>>>(spk, k0, k1, k2, fsc, out);
    bn_stats_k<<<dim3(STATB), dim3(H_DIM), 0, stream>>>(out, part);
    bn_final_k<<<dim3(1), dim3(H_DIM), 0, stream>>>(part, sc, sh, gam, bb, l);
    if(l < NL-1) lif_k<unsigned char><<<dim3(NBH/64), dim3(64), 0, stream>>>(out, spkd, sc, sh, beta, U0, l);
    else         lif_k<float>        <<<dim3(NBH/64), dim3(64), 0, stream>>>(out, out, sc, sh, beta, U0, l);
  }
}